// Round 1
// 259.773 us; speedup vs baseline: 1.0995x; 1.0995x over previous
//
#include <hip/hip_runtime.h>

// KNN top-16: B=4, N=M=8192, C=3.  (GOLD METRIC LOCKED by R17, absmax=0:
//   norms = (x²+z²)+y² [hsum, plain]; cross = fma(z,z',fma(y,y',x*x'));
//   d2 = max((q2+r2) - 2*cross, 0); stable (d2,idx) ascending; 0-based.)
// R20: selection rebuilt on packed u64 keys ((d2bits<<32)|gidx — lex order
//   == jax stable top-k order, since d2>=0 makes IEEE bits monotonic).
//  - Persistent cross-tile candidate buffer (sd=d2bits, sg=gidx): no forced
//    per-tile compact; compacts only on TRIG + one final (~6-10 total).
//  - Batched compact: Batcher sort16 (63 CE) + bitonic merge-16-keep-low
//    (16 min-rev + 32 CE clean). ~45 VALU/entry vs ~120 for insert16.
//  - Fill: first 16 pts/thread -> keys -> one sort16 (kills tile-0 storm).
//  - Final merge: register shfl_xor tree (3 levels), md LDS deleted.
//  - TPB=128/QPB=16: 2048 blocks, LDS 20KB -> 8 blocks/CU = 16 waves/CU.

#define TPB 128
#define QPB 16   // queries per block
#define SPL 8    // threads per query
#define KK 16
#define TILE_PTS 512
#define CAP 16   // LDS candidate slots per thread
#define TRIG 8   // compaction trigger (checked every 8; 7+8 <= 16)

typedef unsigned long long u64k;

#define CE(x, i, j)                                   \
  {                                                   \
    u64k ki_ = x[i], kj_ = x[j];                      \
    bool c_ = kj_ < ki_;                              \
    x[i] = c_ ? kj_ : ki_;                            \
    x[j] = c_ ? ki_ : kj_;                            \
  }

// Batcher odd-even mergesort, 16 elements, 63 comparators.
__device__ __forceinline__ void sort16(u64k x[KK]) {
  CE(x,0,1) CE(x,2,3) CE(x,4,5) CE(x,6,7) CE(x,8,9) CE(x,10,11) CE(x,12,13) CE(x,14,15)
  CE(x,0,2) CE(x,1,3) CE(x,4,6) CE(x,5,7) CE(x,8,10) CE(x,9,11) CE(x,12,14) CE(x,13,15)
  CE(x,1,2) CE(x,5,6) CE(x,9,10) CE(x,13,14)
  CE(x,0,4) CE(x,1,5) CE(x,2,6) CE(x,3,7) CE(x,8,12) CE(x,9,13) CE(x,10,14) CE(x,11,15)
  CE(x,2,4) CE(x,3,5) CE(x,10,12) CE(x,11,13)
  CE(x,1,2) CE(x,3,4) CE(x,5,6) CE(x,9,10) CE(x,11,12) CE(x,13,14)
  CE(x,0,8) CE(x,1,9) CE(x,2,10) CE(x,3,11) CE(x,4,12) CE(x,5,13) CE(x,6,14) CE(x,7,15)
  CE(x,4,8) CE(x,5,9) CE(x,6,10) CE(x,7,11)
  CE(x,2,4) CE(x,3,5) CE(x,6,8) CE(x,7,9) CE(x,10,12) CE(x,11,13)
  CE(x,1,2) CE(x,3,4) CE(x,5,6) CE(x,7,8) CE(x,9,10) CE(x,11,12) CE(x,13,14)
}

// a asc, e asc -> a = 16 smallest of (a ∪ e), ascending.
// min(a[i], e[15-i]) is the low half of the first bitonic stage on
// a ++ reverse(e): contains the 16 smallest and is itself bitonic.
__device__ __forceinline__ void mergeTop16(u64k a[KK], u64k e[KK]) {
#pragma unroll
  for (int i = 0; i < KK; ++i) {
    u64k bv = e[KK - 1 - i];
    if (bv < a[i]) a[i] = bv;
  }
  // bitonic clean (distances 8,4,2,1)
  CE(a,0,8) CE(a,1,9) CE(a,2,10) CE(a,3,11) CE(a,4,12) CE(a,5,13) CE(a,6,14) CE(a,7,15)
  CE(a,0,4) CE(a,1,5) CE(a,2,6) CE(a,3,7) CE(a,8,12) CE(a,9,13) CE(a,10,14) CE(a,11,15)
  CE(a,0,2) CE(a,1,3) CE(a,4,6) CE(a,5,7) CE(a,8,10) CE(a,9,11) CE(a,12,14) CE(a,13,15)
  CE(a,0,1) CE(a,2,3) CE(a,4,5) CE(a,6,7) CE(a,8,9) CE(a,10,11) CE(a,12,13) CE(a,14,15)
}

__global__ __launch_bounds__(TPB, 4) void knn_topk_kernel(
    const float* __restrict__ ref, const float* __restrict__ query,
    float* __restrict__ dout, float* __restrict__ iout, int N, int M) {
#pragma clang fp contract(off)
  __shared__ float4 tile[TILE_PTS];         // 8 KB: x,y,z,r2
  __shared__ unsigned int sd[CAP * TPB];    // 8 KB: candidate d2bits (clamped)
  __shared__ unsigned short sg[CAP * TPB];  // 4 KB: candidate global idx

  const int tid = threadIdx.x;
  const int h = tid & (SPL - 1);
  const int qid = blockIdx.x * QPB + (tid >> 3);
  const int b = qid / M;

  const float* qp = query + (size_t)qid * 3;
  const float qx = qp[0], qy = qp[1], qz = qp[2];
  // HSUM norm (SSE2 movehl reduction of [x2,y2,z2,0]): (x2 + z2) + y2
  float q2 = (qx * qx + qz * qz) + qy * qy;

  u64k kl[KK];  // sorted ascending (d2bits<<32 | gidx) = lex (d2, idx)
  float T;      // shared screen threshold (min of 8 threads' 16th)
  int cnt = 0;

  const float* refb = ref + (size_t)b * N * 3;

  // Batched compact: pull pending (d2bits,gidx) pairs, sort, merge into kl.
  // Wave-uniform call sites only (uses cross-lane shuffles).
  auto compact = [&]() {
    u64k e[KK];
#pragma unroll
    for (int s = 0; s < KK; ++s) {
      unsigned int db = sd[s * TPB + tid];
      unsigned int gi = sg[s * TPB + tid];
      u64k key = ((u64k)db << 32) | gi;
      e[s] = (s < cnt) ? key : ~0ull;  // pads sort to the top, fall out
    }
    sort16(e);
    mergeTop16(kl, e);
    cnt = 0;
    float a15 = __uint_as_float((unsigned)(kl[KK - 1] >> 32));
    float m = fminf(a15, __shfl_xor(a15, 1));
    m = fminf(m, __shfl_xor(m, 2));
    T = fminf(m, __shfl_xor(m, 4));
  };

  const int ntiles = N / TILE_PTS;
  for (int t = 0; t < ntiles; ++t) {
    __syncthreads();
    {
      // Stage 4 points/thread via 3 float4 loads (48 B, 16B-aligned).
      int pl = tid * 4;
      const float4* rp =
          (const float4*)(refb + (size_t)(t * TILE_PTS + pl) * 3);
      float4 f0 = rp[0], f1 = rp[1], f2 = rp[2];
      float x0 = f0.x, y0 = f0.y, z0 = f0.z;
      float x1 = f0.w, y1 = f1.x, z1 = f1.y;
      float x2 = f1.z, y2 = f1.w, z2 = f2.x;
      float x3 = f2.y, y3 = f2.z, z3 = f2.w;
      tile[pl + 0] = make_float4(x0, y0, z0, (x0 * x0 + z0 * z0) + y0 * y0);
      tile[pl + 1] = make_float4(x1, y1, z1, (x1 * x1 + z1 * z1) + y1 * y1);
      tile[pl + 2] = make_float4(x2, y2, z2, (x2 * x2 + z2 * z2) + y2 * y2);
      tile[pl + 3] = make_float4(x3, y3, z3, (x3 * x3 + z3 * z3) + y3 * y3);
    }
    __syncthreads();
    const int tbase = t * TILE_PTS;
    int g0 = 0;
    if (t == 0) {
      // Fill: first 16 arrivals (locs n*8+h), exact metric chain, one sort.
      // Equivalent to 16 sequential inserts into the 3e38-sentinel list.
#pragma unroll
      for (int n = 0; n < KK; ++n) {
        float4 p = tile[n * SPL + h];
        float cr = qx * p.x;
        cr = __builtin_fmaf(qy, p.y, cr);
        cr = __builtin_fmaf(qz, p.z, cr);
        float s2 = q2 + p.w;
        float d2 = __builtin_fmaf(-2.0f, cr, s2);
        float d2c = d2 < 0.f ? 0.f : d2;
        kl[n] = ((u64k)__float_as_uint(d2c) << 32) | (unsigned)(n * SPL + h);
      }
      sort16(kl);
      float a15 = __uint_as_float((unsigned)(kl[KK - 1] >> 32));
      float m = fminf(a15, __shfl_xor(a15, 1));
      m = fminf(m, __shfl_xor(m, 2));
      T = fminf(m, __shfl_xor(m, 4));
      g0 = 16;
    }
    for (int g = g0; g < TILE_PTS / SPL; g += 8) {
#pragma unroll
      for (int u = 0; u < 8; ++u) {
        const int loc = (g + u) * SPL + h;  // subset h: refs ≡ h (mod 8)
        float4 p = tile[loc];
        // cross = ascending-k FMA chain (BLAS sgemm microkernel):
        float cr = qx * p.x;
        cr = __builtin_fmaf(qy, p.y, cr);
        cr = __builtin_fmaf(qz, p.z, cr);
        float s2 = q2 + p.w;                       // (q2 + r2), one rounding
        float d2 = __builtin_fmaf(-2.0f, cr, s2);  // == round(s2 - 2*cr)
        if (d2 <= T) {  // conservative shared screen (<= keeps exact ties)
          float d2c = d2 < 0.f ? 0.f : d2;
          sd[cnt * TPB + tid] = __float_as_uint(d2c);
          sg[cnt * TPB + tid] = (unsigned short)(tbase + loc);
          cnt++;
        }
      }
      if (__any(cnt >= TRIG)) compact();  // wave-synchronized
    }
    // no forced per-tile compact: entries carry global idx + exact d2bits
  }
  if (__any(cnt > 0)) compact();  // resolve stragglers

  // Cross-lane tree merge over the 8 subset threads (all lanes symmetric:
  // min(A[i],B[15-i]) is symmetric in A,B up to reversal; clean re-sorts).
#pragma unroll
  for (int d = 1; d < SPL; d <<= 1) {
    u64k r[KK];
#pragma unroll
    for (int s = 0; s < KK; ++s) r[s] = __shfl_xor(kl[s], d);
    mergeTop16(kl, r);
  }

  if (h == 0) {
    float* dq = dout + (size_t)qid * KK;
    float* iq = iout + (size_t)qid * KK;
    float dv[KK], iv[KK];
#pragma unroll
    for (int o = 0; o < KK; ++o) {
      dv[o] = sqrtf(__uint_as_float((unsigned)(kl[o] >> 32)));
      iv[o] = (float)(unsigned)(kl[o] & 0xffffffffu);  // 0-based
    }
    ((float4*)dq)[0] = make_float4(dv[0], dv[1], dv[2], dv[3]);
    ((float4*)dq)[1] = make_float4(dv[4], dv[5], dv[6], dv[7]);
    ((float4*)dq)[2] = make_float4(dv[8], dv[9], dv[10], dv[11]);
    ((float4*)dq)[3] = make_float4(dv[12], dv[13], dv[14], dv[15]);
    ((float4*)iq)[0] = make_float4(iv[0], iv[1], iv[2], iv[3]);
    ((float4*)iq)[1] = make_float4(iv[4], iv[5], iv[6], iv[7]);
    ((float4*)iq)[2] = make_float4(iv[8], iv[9], iv[10], iv[11]);
    ((float4*)iq)[3] = make_float4(iv[12], iv[13], iv[14], iv[15]);
  }
}

extern "C" void kernel_launch(void* const* d_in, const int* in_sizes, int n_in,
                              void* d_out, int out_size, void* d_ws, size_t ws_size,
                              hipStream_t stream) {
  const float* ref = (const float*)d_in[0];
  const float* query = (const float*)d_in[1];
  const int B = 4, C = 3;
  int N = in_sizes[0] / (B * C);
  int M = in_sizes[1] / (B * C);
  float* dout = (float*)d_out;
  float* iout = dout + (size_t)out_size / 2;  // idx half, written as float
  int totalQ = B * M;
  int blocks = totalQ / QPB;
  knn_topk_kernel<<<blocks, TPB, 0, stream>>>(ref, query, dout, iout, N, M);
}